// Round 1
// baseline (12312.862 us; speedup 1.0000x reference)
//
#include <hip/hip_runtime.h>
#include <math.h>

// ---------------------------------------------------------------------------
// GCN: x1 = relu(GCNConv(x, W1, b1)); x2 = relu(GCNConv(x1, W2, b2))
//      h = [x, x1, x2]; out = sigmoid(relu(h @ Wl1 + bl1) @ Wl2 + bl2)
// GCNConv(x) = Dinv (A) Dinv (xW) + Dinv^2 (xW) + b   (self loop)
// ---------------------------------------------------------------------------

#define HID 128

__global__ void k_init_deg(float* deg, int n) {
    int i = blockIdx.x * blockDim.x + threadIdx.x;
    if (i < n) deg[i] = 1.0f;
}

__global__ void k_count_deg(const int* __restrict__ col, float* deg, int e) {
    int i = blockIdx.x * blockDim.x + threadIdx.x;
    if (i < e) atomicAdd(&deg[col[i]], 1.0f);
}

__global__ void k_rsqrt(float* deg, int n) {
    int i = blockIdx.x * blockDim.x + threadIdx.x;
    if (i < n) deg[i] = rsqrtf(deg[i]);
}

// Y[n x 128] = X[n x 128] @ W[128 x 128] (+ bias) (+= if accum)
__global__ __launch_bounds__(256) void k_gemm128(
    const float* __restrict__ X, const float* __restrict__ W,
    const float* __restrict__ bias, float* __restrict__ Y, int n, int accum) {
    __shared__ float Wl[128 * 128];      // 64 KB
    __shared__ float Xl[2][128];
    for (int i = threadIdx.x; i < 128 * 128; i += 256) Wl[i] = W[i];
    __syncthreads();
    int tc = threadIdx.x & 127;          // output channel
    int th = threadIdx.x >> 7;           // 0..1 (node within pair)
    int base = blockIdx.x * 64;
    for (int r = 0; r < 64; r += 2) {
        int node = base + r + th;
        bool ok = node < n;
        if (ok) Xl[th][tc] = X[(size_t)node * 128 + tc];
        __syncthreads();
        if (ok) {
            float a0 = 0.f, a1 = 0.f, a2 = 0.f, a3 = 0.f;
#pragma unroll
            for (int k = 0; k < 128; k += 4) {
                a0 = fmaf(Xl[th][k + 0], Wl[(k + 0) * 128 + tc], a0);
                a1 = fmaf(Xl[th][k + 1], Wl[(k + 1) * 128 + tc], a1);
                a2 = fmaf(Xl[th][k + 2], Wl[(k + 2) * 128 + tc], a2);
                a3 = fmaf(Xl[th][k + 3], Wl[(k + 3) * 128 + tc], a3);
            }
            float acc = (a0 + a1) + (a2 + a3);
            if (bias) acc += bias[tc];
            size_t idx = (size_t)node * 128 + tc;
            Y[idx] = accum ? (Y[idx] + acc) : acc;
        }
        __syncthreads();
    }
}

// agg[i][c] = xw[i][c] * dinv[i]^2 + b[c]   (self-loop term + bias as init)
__global__ void k_init_agg(const float* __restrict__ xw,
                           const float* __restrict__ dinv,
                           const float* __restrict__ bias,
                           float* __restrict__ agg, int n) {
    long long i = (long long)blockIdx.x * blockDim.x + threadIdx.x;
    long long total = (long long)n * 32;            // float4 granularity
    if (i >= total) return;
    int node = (int)(i >> 5);
    int c4 = ((int)i & 31) * 4;
    float s = dinv[node]; s = s * s;
    float4 v = *(const float4*)(xw + (size_t)node * 128 + c4);
    float4 b = *(const float4*)(bias + c4);
    float4 o = make_float4(fmaf(v.x, s, b.x), fmaf(v.y, s, b.y),
                           fmaf(v.z, s, b.z), fmaf(v.w, s, b.w));
    *(float4*)(agg + (size_t)node * 128 + c4) = o;
}

// agg[col] += xw[row] * dinv[row]*dinv[col], 32 lanes (float4 each) per edge
__global__ void k_scatter(const int* __restrict__ row, const int* __restrict__ col,
                          const float* __restrict__ dinv,
                          const float* __restrict__ xw,
                          float* __restrict__ agg, int e) {
    long long t = (long long)blockIdx.x * blockDim.x + threadIdx.x;
    long long eid = t >> 5;
    if (eid >= e) return;
    int c4 = ((int)t & 31) * 4;
    int r = row[eid], c = col[eid];
    float norm = dinv[r] * dinv[c];
    float4 v = *(const float4*)(xw + (size_t)r * 128 + c4);
    float* dst = agg + (size_t)c * 128 + c4;
    atomicAdd(dst + 0, v.x * norm);
    atomicAdd(dst + 1, v.y * norm);
    atomicAdd(dst + 2, v.z * norm);
    atomicAdd(dst + 3, v.w * norm);
}

__global__ void k_relu(float* __restrict__ a, long long n4) {
    long long i = (long long)blockIdx.x * blockDim.x + threadIdx.x;
    if (i >= n4) return;
    float4 v = *(float4*)(a + i * 4);
    v.x = fmaxf(v.x, 0.f); v.y = fmaxf(v.y, 0.f);
    v.z = fmaxf(v.z, 0.f); v.w = fmaxf(v.w, 0.f);
    *(float4*)(a + i * 4) = v;
}

// out[node] = sigmoid( sum_j relu(hid[node][j]) * Wl2[j] + bl2 ), wave per node
__global__ void k_mlp_out(const float* __restrict__ hid,
                          const float* __restrict__ Wl2,
                          const float* __restrict__ bl2,
                          float* __restrict__ out, int n) {
    long long t = (long long)blockIdx.x * blockDim.x + threadIdx.x;
    int node = (int)(t >> 6);
    int lane = (int)t & 63;
    if (node >= n) return;
    const float* h = hid + (size_t)node * 128;
    float a = fmaxf(h[lane], 0.f) * Wl2[lane] +
              fmaxf(h[lane + 64], 0.f) * Wl2[lane + 64];
    for (int off = 32; off; off >>= 1) a += __shfl_down(a, off);
    if (lane == 0) out[node] = 1.f / (1.f + expf(-(a + bl2[0])));
}

extern "C" void kernel_launch(void* const* d_in, const int* in_sizes, int n_in,
                              void* d_out, int out_size, void* d_ws, size_t ws_size,
                              hipStream_t stream) {
    const float* x   = (const float*)d_in[0];
    const int*   ei  = (const int*)d_in[1];
    const float* W1  = (const float*)d_in[2];
    const float* b1  = (const float*)d_in[3];
    const float* W2  = (const float*)d_in[4];
    const float* b2  = (const float*)d_in[5];
    const float* Wl1 = (const float*)d_in[6];
    const float* bl1 = (const float*)d_in[7];
    const float* Wl2 = (const float*)d_in[8];
    const float* bl2 = (const float*)d_in[9];
    float* out = (float*)d_out;

    const int N = in_sizes[0] / 128;
    const int E = in_sizes[1] / 2;
    const int* row = ei;
    const int* col = ei + E;

    char* ws = (char*)d_ws;
    size_t off = 0;
    float* dinv = (float*)(ws + off); off += ((size_t)N * 4 + 255) & ~(size_t)255;
    float* bufA = (float*)(ws + off); off += (size_t)N * 128 * 4;   // xw1 -> xw2 -> hid
    float* bufB = (float*)(ws + off); off += (size_t)N * 128 * 4;   // agg1 -> x1
    float* bufC = (float*)(ws + off); off += (size_t)N * 128 * 4;   // agg2 -> x2

    const int B = 256;
    int gN = (N + B - 1) / B;
    int gE = (E + B - 1) / B;
    long long n4 = (long long)N * 32;                 // float4 count for N*128
    int g4 = (int)((n4 + B - 1) / B);
    long long st = (long long)E * 32;                 // scatter threads
    int gS = (int)((st + B - 1) / B);
    int gG = (N + 63) / 64;                           // gemm blocks
    int gO = (int)(((long long)N * 64 + B - 1) / B);  // wave per node

    // degrees
    k_init_deg<<<gN, B, 0, stream>>>(dinv, N);
    k_count_deg<<<gE, B, 0, stream>>>(col, dinv, E);
    k_rsqrt<<<gN, B, 0, stream>>>(dinv, N);

    // layer 1
    k_gemm128<<<gG, B, 0, stream>>>(x, W1, nullptr, bufA, N, 0);
    k_init_agg<<<g4, B, 0, stream>>>(bufA, dinv, b1, bufB, N);
    k_scatter<<<gS, B, 0, stream>>>(row, col, dinv, bufA, bufB, E);
    k_relu<<<g4, B, 0, stream>>>(bufB, n4);

    // layer 2
    k_gemm128<<<gG, B, 0, stream>>>(bufB, W2, nullptr, bufA, N, 0);
    k_init_agg<<<g4, B, 0, stream>>>(bufA, dinv, b2, bufC, N);
    k_scatter<<<gS, B, 0, stream>>>(row, col, dinv, bufA, bufC, E);
    k_relu<<<g4, B, 0, stream>>>(bufC, n4);

    // MLP head: hid = x@Wl1[0:128] + x1@Wl1[128:256] + x2@Wl1[256:384] + bl1
    k_gemm128<<<gG, B, 0, stream>>>(x,    Wl1,              bl1,     bufA, N, 0);
    k_gemm128<<<gG, B, 0, stream>>>(bufB, Wl1 + 128 * 128, nullptr, bufA, N, 1);
    k_gemm128<<<gG, B, 0, stream>>>(bufC, Wl1 + 256 * 128, nullptr, bufA, N, 1);
    k_mlp_out<<<gO, B, 0, stream>>>(bufA, Wl2, bl2, out, N);
}

// Round 2
// 2201.222 us; speedup vs baseline: 5.5936x; 5.5936x over previous
//
#include <hip/hip_runtime.h>
#include <math.h>

// ---------------------------------------------------------------------------
// GCN via CSR gather (no float atomics):
//   cnt = histogram(col); dinv = rsqrt(cnt+1); offs = exclusive_scan(cnt)
//   srow = edges sorted by col (counting sort)
//   xws  = (X @ W) * dinv[node]              (GEMM epilogue fusion)
//   x_out[n] = relu(dinv[n]*(xws[n] + sum_{e in CSR[n]} xws[srow[e]]) + b)
// ---------------------------------------------------------------------------

__global__ void k_hist(const int* __restrict__ col, int* __restrict__ cnt, int e) {
    int i = blockIdx.x * blockDim.x + threadIdx.x;
    if (i < e) atomicAdd(&cnt[col[i]], 1);
}

__global__ void k_dinv(const int* __restrict__ cnt, float* __restrict__ dinv, int n) {
    int i = blockIdx.x * blockDim.x + threadIdx.x;
    if (i < n) dinv[i] = rsqrtf((float)cnt[i] + 1.0f);
}

// per-block exclusive scan of cnt -> offs, block totals -> bsum
__global__ __launch_bounds__(256) void k_scan1(const int* __restrict__ cnt,
                                               int* __restrict__ offs,
                                               int* __restrict__ bsum, int n) {
    __shared__ int s[256];
    int t = threadIdx.x;
    int i = blockIdx.x * 256 + t;
    int v = (i < n) ? cnt[i] : 0;
    s[t] = v;
    __syncthreads();
    for (int d = 1; d < 256; d <<= 1) {
        int add = (t >= d) ? s[t - d] : 0;
        __syncthreads();
        s[t] += add;
        __syncthreads();
    }
    if (i < n) offs[i] = s[t] - v;          // exclusive within block
    if (t == 255) bsum[blockIdx.x] = s[255];
}

// single-block scan of block sums (loop with carry)
__global__ __launch_bounds__(256) void k_scan2(int* __restrict__ bsum, int nb) {
    __shared__ int s[256];
    __shared__ int carry_s;
    int t = threadIdx.x;
    if (t == 0) carry_s = 0;
    __syncthreads();
    for (int base = 0; base < nb; base += 256) {
        int v = (base + t < nb) ? bsum[base + t] : 0;
        s[t] = v;
        __syncthreads();
        for (int d = 1; d < 256; d <<= 1) {
            int add = (t >= d) ? s[t - d] : 0;
            __syncthreads();
            s[t] += add;
            __syncthreads();
        }
        int total = s[255];
        int excl = s[t] - v;
        int c = carry_s;
        if (base + t < nb) bsum[base + t] = excl + c;
        __syncthreads();
        if (t == 0) carry_s = c + total;
        __syncthreads();
    }
}

__global__ void k_scan3(int* __restrict__ offs, const int* __restrict__ bsum,
                        int n, int e) {
    int i = blockIdx.x * blockDim.x + threadIdx.x;
    if (i < n) offs[i] += bsum[i >> 8];
    if (i == 0) offs[n] = e;
}

// counting-sort edge ids: srow[slot] = row, slots grouped by col
__global__ void k_fill(const int* __restrict__ row, const int* __restrict__ col,
                       const int* __restrict__ offs, int* __restrict__ cur,
                       int* __restrict__ srow, int e) {
    int i = blockIdx.x * blockDim.x + threadIdx.x;
    if (i >= e) return;
    int c = col[i];
    int pos = offs[c] + atomicAdd(&cur[c], 1);
    srow[pos] = row[i];
}

// Y[n x 128] = (X[n x 128] @ W[128 x 128]) [* dinv[node]] [+ bias] [+= Y]
__global__ __launch_bounds__(256) void k_gemm128(
    const float* __restrict__ X, const float* __restrict__ W,
    const float* __restrict__ bias, const float* __restrict__ dscale,
    float* __restrict__ Y, int n, int accum) {
    __shared__ float Wl[128 * 128];      // 64 KB
    __shared__ float Xl[2][128];
    for (int i = threadIdx.x; i < 128 * 128; i += 256) Wl[i] = W[i];
    __syncthreads();
    int tc = threadIdx.x & 127;          // output channel
    int th = threadIdx.x >> 7;           // 0..1 (node within pair)
    int base = blockIdx.x * 64;
    for (int r = 0; r < 64; r += 2) {
        int node = base + r + th;
        bool ok = node < n;
        if (ok) Xl[th][tc] = X[(size_t)node * 128 + tc];
        __syncthreads();
        if (ok) {
            float a0 = 0.f, a1 = 0.f, a2 = 0.f, a3 = 0.f;
#pragma unroll
            for (int k = 0; k < 128; k += 4) {
                a0 = fmaf(Xl[th][k + 0], Wl[(k + 0) * 128 + tc], a0);
                a1 = fmaf(Xl[th][k + 1], Wl[(k + 1) * 128 + tc], a1);
                a2 = fmaf(Xl[th][k + 2], Wl[(k + 2) * 128 + tc], a2);
                a3 = fmaf(Xl[th][k + 3], Wl[(k + 3) * 128 + tc], a3);
            }
            float acc = (a0 + a1) + (a2 + a3);
            if (dscale) acc *= dscale[node];
            if (bias) acc += bias[tc];
            size_t idx = (size_t)node * 128 + tc;
            Y[idx] = accum ? (Y[idx] + acc) : acc;
        }
        __syncthreads();
    }
}

// out[n] = relu(dinv[n]*(xws[n] + sum_e xws[srow[e]]) + bias), wave per node
__global__ __launch_bounds__(256) void k_aggregate(
    const float* __restrict__ xws, const float* __restrict__ dinv,
    const float* __restrict__ bias, const int* __restrict__ offs,
    const int* __restrict__ srow, float* __restrict__ out, int n) {
    long long t = (long long)blockIdx.x * blockDim.x + threadIdx.x;
    int node = (int)(t >> 6);
    int c2 = ((int)t & 63) * 2;
    if (node >= n) return;
    int start = offs[node], end = offs[node + 1];
    float2 acc = *(const float2*)(xws + (size_t)node * 128 + c2);
    for (int e = start; e < end; ++e) {
        int r = srow[e];                  // uniform per wave -> broadcast
        float2 v = *(const float2*)(xws + (size_t)r * 128 + c2);
        acc.x += v.x;
        acc.y += v.y;
    }
    float s = dinv[node];
    float2 b = *(const float2*)(bias + c2);
    acc.x = fmaxf(fmaf(acc.x, s, b.x), 0.f);
    acc.y = fmaxf(fmaf(acc.y, s, b.y), 0.f);
    *(float2*)(out + (size_t)node * 128 + c2) = acc;
}

// out[node] = sigmoid( sum_j relu(hid[node][j]) * Wl2[j] + bl2 ), wave per node
__global__ void k_mlp_out(const float* __restrict__ hid,
                          const float* __restrict__ Wl2,
                          const float* __restrict__ bl2,
                          float* __restrict__ out, int n) {
    long long t = (long long)blockIdx.x * blockDim.x + threadIdx.x;
    int node = (int)(t >> 6);
    int lane = (int)t & 63;
    if (node >= n) return;
    const float* h = hid + (size_t)node * 128;
    float a = fmaxf(h[lane], 0.f) * Wl2[lane] +
              fmaxf(h[lane + 64], 0.f) * Wl2[lane + 64];
    for (int off = 32; off; off >>= 1) a += __shfl_down(a, off);
    if (lane == 0) out[node] = 1.f / (1.f + expf(-(a + bl2[0])));
}

extern "C" void kernel_launch(void* const* d_in, const int* in_sizes, int n_in,
                              void* d_out, int out_size, void* d_ws, size_t ws_size,
                              hipStream_t stream) {
    const float* x   = (const float*)d_in[0];
    const int*   ei  = (const int*)d_in[1];
    const float* W1  = (const float*)d_in[2];
    const float* b1  = (const float*)d_in[3];
    const float* W2  = (const float*)d_in[4];
    const float* b2  = (const float*)d_in[5];
    const float* Wl1 = (const float*)d_in[6];
    const float* bl1 = (const float*)d_in[7];
    const float* Wl2 = (const float*)d_in[8];
    const float* bl2 = (const float*)d_in[9];
    float* out = (float*)d_out;

    const int N = in_sizes[0] / 128;
    const int E = in_sizes[1] / 2;
    const int* row = ei;
    const int* col = ei + E;
    const int nb = (N + 255) / 256;

    char* ws = (char*)d_ws;
    size_t off = 0;
    auto alloc = [&](size_t bytes) {
        void* p = ws + off;
        off += (bytes + 255) & ~(size_t)255;
        return p;
    };
    float* dinv = (float*)alloc((size_t)N * 4);
    int*   cnt  = (int*)alloc((size_t)N * 4);
    int*   offs = (int*)alloc((size_t)(N + 1) * 4);
    int*   cur  = (int*)alloc((size_t)N * 4);
    int*   bsum = (int*)alloc((size_t)nb * 4);
    int*   srow = (int*)alloc((size_t)E * 4);
    float* bufA = (float*)alloc((size_t)N * 128 * 4);   // xws1 -> xws2 -> hid
    float* bufB = (float*)alloc((size_t)N * 128 * 4);   // x1
    float* bufC = (float*)alloc((size_t)N * 128 * 4);   // x2

    const int B = 256;
    int gN = (N + B - 1) / B;
    int gE = (E + B - 1) / B;
    int gG = (N + 63) / 64;                             // gemm blocks
    int gA = (int)(((long long)N * 64 + B - 1) / B);    // wave per node

    // ---- CSR build ----
    hipMemsetAsync(cnt, 0, (size_t)N * 4, stream);
    hipMemsetAsync(cur, 0, (size_t)N * 4, stream);
    k_hist<<<gE, B, 0, stream>>>(col, cnt, E);
    k_dinv<<<gN, B, 0, stream>>>(cnt, dinv, N);
    k_scan1<<<nb, B, 0, stream>>>(cnt, offs, bsum, N);
    k_scan2<<<1, B, 0, stream>>>(bsum, nb);
    k_scan3<<<gN, B, 0, stream>>>(offs, bsum, N, E);
    k_fill<<<gE, B, 0, stream>>>(row, col, offs, cur, srow, E);

    // ---- layer 1 ----
    k_gemm128<<<gG, B, 0, stream>>>(x, W1, nullptr, dinv, bufA, N, 0);
    k_aggregate<<<gA, B, 0, stream>>>(bufA, dinv, b1, offs, srow, bufB, N);

    // ---- layer 2 ----
    k_gemm128<<<gG, B, 0, stream>>>(bufB, W2, nullptr, dinv, bufA, N, 0);
    k_aggregate<<<gA, B, 0, stream>>>(bufA, dinv, b2, offs, srow, bufC, N);

    // ---- MLP head: hid = x@Wl1[0:128] + x1@Wl1[128:256] + x2@Wl1[256:384] + bl1
    k_gemm128<<<gG, B, 0, stream>>>(x,    Wl1,             bl1,     nullptr, bufA, N, 0);
    k_gemm128<<<gG, B, 0, stream>>>(bufB, Wl1 + 128 * 128, nullptr, nullptr, bufA, N, 1);
    k_gemm128<<<gG, B, 0, stream>>>(bufC, Wl1 + 256 * 128, nullptr, nullptr, bufA, N, 1);
    k_mlp_out<<<gA, B, 0, stream>>>(bufA, Wl2, bl2, out, N);
}

// Round 4
// 912.757 us; speedup vs baseline: 13.4897x; 2.4116x over previous
//
#include <hip/hip_runtime.h>
#include <math.h>

// ---------------------------------------------------------------------------
// GCN, CSR-gather aggregation + split-bf16 MFMA GEMMs.
//   xws  = (X @ W) * dinv[node]         (MFMA GEMM, hi/lo split, fp32-accurate)
//   x_out[n] = relu(dinv[n]*(xws[n] + sum_{e in CSR[n]} xws[srow[e]]) + b)
//   out = sigmoid(relu([x,x1,x2]@Wl1 + bl1) @ Wl2 + bl2)   (single fused kernel)
// MFMA k-slot mapping q(g,j) = 4g+j (j<4), 16+4g+(j-4) (j>=4) applied
// identically to A and B fragments -> correctness independent of HW k order.
// ---------------------------------------------------------------------------

typedef __attribute__((ext_vector_type(8))) short bf16x8;
typedef __attribute__((ext_vector_type(4))) float f32x4;

// ---------------- CSR build ----------------
__global__ void k_hist(const int* __restrict__ col, int* __restrict__ cnt, int e) {
    int i = blockIdx.x * blockDim.x + threadIdx.x;
    if (i < e) atomicAdd(&cnt[col[i]], 1);
}

__global__ void k_dinv(const int* __restrict__ cnt, float* __restrict__ dinv, int n) {
    int i = blockIdx.x * blockDim.x + threadIdx.x;
    if (i < n) dinv[i] = rsqrtf((float)cnt[i] + 1.0f);
}

__global__ __launch_bounds__(256) void k_scan1(const int* __restrict__ cnt,
                                               int* __restrict__ offs,
                                               int* __restrict__ bsum, int n) {
    __shared__ int s[256];
    int t = threadIdx.x;
    int i = blockIdx.x * 256 + t;
    int v = (i < n) ? cnt[i] : 0;
    s[t] = v;
    __syncthreads();
    for (int d = 1; d < 256; d <<= 1) {
        int add = (t >= d) ? s[t - d] : 0;
        __syncthreads();
        s[t] += add;
        __syncthreads();
    }
    if (i < n) offs[i] = s[t] - v;
    if (t == 255) bsum[blockIdx.x] = s[255];
}

__global__ __launch_bounds__(256) void k_scan2(int* __restrict__ bsum, int nb) {
    __shared__ int s[256];
    __shared__ int carry_s;
    int t = threadIdx.x;
    if (t == 0) carry_s = 0;
    __syncthreads();
    for (int base = 0; base < nb; base += 256) {
        int v = (base + t < nb) ? bsum[base + t] : 0;
        s[t] = v;
        __syncthreads();
        for (int d = 1; d < 256; d <<= 1) {
            int add = (t >= d) ? s[t - d] : 0;
            __syncthreads();
            s[t] += add;
            __syncthreads();
        }
        int total = s[255];
        int excl = s[t] - v;
        int c = carry_s;
        if (base + t < nb) bsum[base + t] = excl + c;
        __syncthreads();
        if (t == 0) carry_s = c + total;
        __syncthreads();
    }
}

__global__ void k_scan3(int* __restrict__ offs, const int* __restrict__ bsum,
                        int n, int e) {
    int i = blockIdx.x * blockDim.x + threadIdx.x;
    if (i < n) offs[i] += bsum[i >> 8];
    if (i == 0) offs[n] = e;
}

__global__ void k_fill(const int* __restrict__ row, const int* __restrict__ col,
                       const int* __restrict__ offs, int* __restrict__ cur,
                       int* __restrict__ srow, int e) {
    int i = blockIdx.x * blockDim.x + threadIdx.x;
    if (i >= e) return;
    int c = col[i];
    int pos = offs[c] + atomicAdd(&cur[c], 1);
    srow[pos] = row[i];
}

// ---------------- weight prep: frag-ordered bf16 hi/lo ----------------
// wb layout per 128x128 block: [hi:16384][lo:16384] shorts, index
// ((kk*8+nt)*64+lane)*8+elem with lane=16g+c, elem=half*4+j, k=kk*32+half*16+4g+j
__global__ void k_prep_w(const float* __restrict__ W1, const float* __restrict__ W2,
                         const float* __restrict__ Wl1, short* __restrict__ wb) {
    int i = blockIdx.x * blockDim.x + threadIdx.x;
    if (i >= 5 * 16384) return;
    int blk = i >> 14, rem = i & 16383;
    int k = rem >> 7, n = rem & 127;
    float v;
    if (blk == 0) v = W1[rem];
    else if (blk == 1) v = W2[rem];
    else v = Wl1[((blk - 2) * 128 + k) * 128 + n];
    unsigned u = __float_as_uint(v);
    unsigned hb = u & 0xFFFF0000u;
    float lo = v - __uint_as_float(hb);
    unsigned lb = __float_as_uint(lo);
    int kk = k >> 5, km = k & 31;
    int half = km >> 4, kq = km & 15, g = kq >> 2, j = kq & 3;
    int nt = n >> 4, c = n & 15;
    size_t idx = ((size_t)(kk * 8 + nt) * 64 + (g * 16 + c)) * 8 + (half * 4 + j);
    size_t base = (size_t)blk * 32768;
    wb[base + idx] = (short)(hb >> 16);
    wb[base + 16384 + idx] = (short)(lb >> 16);
}

__device__ inline short2 split_f(float x) {
    unsigned u = __float_as_uint(x);
    unsigned hb = u & 0xFFFF0000u;
    short h = (short)(u >> 16);
    short l = (short)(__float_as_uint(x - __uint_as_float(hb)) >> 16);
    return make_short2(h, l);
}

// ---------------- MFMA GEMM ----------------
// mode 0: Y[node][ch] = (src0 @ Wblk) * dscale[node]           (nkb=1)
// mode 1: out[node]   = sigmoid(relu(sum_kb srcKB@Wblk + bl1) . wl2 + bl2)  (nkb=3)
__global__ __launch_bounds__(256) void k_gemm_mfma(
    const float* __restrict__ src0, const float* __restrict__ src1,
    const float* __restrict__ src2, const short* __restrict__ wb,
    const float* __restrict__ dscale, const float* __restrict__ bias,
    const float* __restrict__ wl2, const float* __restrict__ bl2,
    float* __restrict__ Y, int n, int nkb, int mode) {
    __shared__ short wl[32768];          // 64 KB: [hi 16384][lo 16384]
    int tid = threadIdx.x;
    int wave = tid >> 6, lane = tid & 63;
    int g = lane >> 4, c = lane & 15;
    int base = blockIdx.x * 128 + wave * 32;

    f32x4 acc[2][8];
#pragma unroll
    for (int a = 0; a < 2; ++a)
#pragma unroll
        for (int b = 0; b < 8; ++b) acc[a][b] = (f32x4){0.f, 0.f, 0.f, 0.f};

    for (int kb = 0; kb < nkb; ++kb) {
        const float* src = (kb == 0) ? src0 : ((kb == 1) ? src1 : src2);
        __syncthreads();
        {
            const int4* s = (const int4*)(wb + (size_t)kb * 32768);
            int4* d = (int4*)wl;
            for (int it = tid; it < 4096; it += 256) d[it] = s[it];
        }
        __syncthreads();
#pragma unroll
        for (int kk = 0; kk < 4; ++kk) {
            bf16x8 ah[2], al[2];
#pragma unroll
            for (int mf = 0; mf < 2; ++mf) {
                int node = base + mf * 16 + c;
                if (node >= n) node = n - 1;     // clamp; stores are guarded
                const float* p = src + (size_t)node * 128 + kk * 32 + g * 4;
                float4 v0 = *(const float4*)p;
                float4 v1 = *(const float4*)(p + 16);
                short2 s;
                s = split_f(v0.x); ah[mf][0] = s.x; al[mf][0] = s.y;
                s = split_f(v0.y); ah[mf][1] = s.x; al[mf][1] = s.y;
                s = split_f(v0.z); ah[mf][2] = s.x; al[mf][2] = s.y;
                s = split_f(v0.w); ah[mf][3] = s.x; al[mf][3] = s.y;
                s = split_f(v1.x); ah[mf][4] = s.x; al[mf][4] = s.y;
                s = split_f(v1.y); ah[mf][5] = s.x; al[mf][5] = s.y;
                s = split_f(v1.z); ah[mf][6] = s.x; al[mf][6] = s.y;
                s = split_f(v1.w); ah[mf][7] = s.x; al[mf][7] = s.y;
            }
#pragma unroll
            for (int nt = 0; nt < 8; ++nt) {
                int bidx = ((kk * 8 + nt) * 64 + lane) * 8;
                bf16x8 bh = *(const bf16x8*)&wl[bidx];
                bf16x8 bl = *(const bf16x8*)&wl[16384 + bidx];
#pragma unroll
                for (int mf = 0; mf < 2; ++mf) {
                    acc[mf][nt] = __builtin_amdgcn_mfma_f32_16x16x32_bf16(ah[mf], bh, acc[mf][nt], 0, 0, 0);
                    acc[mf][nt] = __builtin_amdgcn_mfma_f32_16x16x32_bf16(ah[mf], bl, acc[mf][nt], 0, 0, 0);
                    acc[mf][nt] = __builtin_amdgcn_mfma_f32_16x16x32_bf16(al[mf], bh, acc[mf][nt], 0, 0, 0);
                }
            }
        }
    }

    if (mode == 0) {
#pragma unroll
        for (int mf = 0; mf < 2; ++mf) {
#pragma unroll
            for (int j = 0; j < 4; ++j) {
                int node = base + mf * 16 + g * 4 + j;   // row=(lane>>4)*4+reg
                if (node >= n) continue;
                float s = dscale[node];
#pragma unroll
                for (int nt = 0; nt < 8; ++nt)
                    Y[(size_t)node * 128 + nt * 16 + c] = acc[mf][nt][j] * s;
            }
        }
    } else {
        float wv[8], bv[8];
#pragma unroll
        for (int nt = 0; nt < 8; ++nt) {
            wv[nt] = wl2[nt * 16 + c];
            bv[nt] = bias[nt * 16 + c];
        }
        float blv = bl2[0];
#pragma unroll
        for (int mf = 0; mf < 2; ++mf) {
#pragma unroll
            for (int j = 0; j < 4; ++j) {
                float partial = 0.f;
#pragma unroll
                for (int nt = 0; nt < 8; ++nt)
                    partial += fmaxf(acc[mf][nt][j] + bv[nt], 0.f) * wv[nt];
#pragma unroll
                for (int m = 1; m < 16; m <<= 1) partial += __shfl_xor(partial, m);
                int node = base + mf * 16 + g * 4 + j;
                if (c == 0 && node < n)
                    Y[node] = 1.f / (1.f + expf(-(partial + blv)));
            }
        }
    }
}

// ---------------- aggregation (gather) ----------------
__global__ __launch_bounds__(256) void k_aggregate(
    const float* __restrict__ xws, const float* __restrict__ dinv,
    const float* __restrict__ bias, const int* __restrict__ offs,
    const int* __restrict__ srow, float* __restrict__ out, int n) {
    long long t = (long long)blockIdx.x * blockDim.x + threadIdx.x;
    int node = (int)(t >> 6);
    int c2 = ((int)t & 63) * 2;
    if (node >= n) return;
    int start = offs[node], end = offs[node + 1];
    float2 acc = *(const float2*)(xws + (size_t)node * 128 + c2);
    int e = start;
    for (; e + 3 < end; e += 4) {
        int r0 = srow[e], r1 = srow[e + 1], r2 = srow[e + 2], r3 = srow[e + 3];
        float2 v0 = *(const float2*)(xws + (size_t)r0 * 128 + c2);
        float2 v1 = *(const float2*)(xws + (size_t)r1 * 128 + c2);
        float2 v2 = *(const float2*)(xws + (size_t)r2 * 128 + c2);
        float2 v3 = *(const float2*)(xws + (size_t)r3 * 128 + c2);
        acc.x += v0.x + v1.x + v2.x + v3.x;
        acc.y += v0.y + v1.y + v2.y + v3.y;
    }
    for (; e < end; ++e) {
        int r = srow[e];
        float2 v = *(const float2*)(xws + (size_t)r * 128 + c2);
        acc.x += v.x;
        acc.y += v.y;
    }
    float s = dinv[node];
    float2 b = *(const float2*)(bias + c2);
    acc.x = fmaxf(fmaf(acc.x, s, b.x), 0.f);
    acc.y = fmaxf(fmaf(acc.y, s, b.y), 0.f);
    *(float2*)(out + (size_t)node * 128 + c2) = acc;
}

extern "C" void kernel_launch(void* const* d_in, const int* in_sizes, int n_in,
                              void* d_out, int out_size, void* d_ws, size_t ws_size,
                              hipStream_t stream) {
    const float* x   = (const float*)d_in[0];
    const int*   ei  = (const int*)d_in[1];
    const float* W1  = (const float*)d_in[2];
    const float* b1  = (const float*)d_in[3];
    const float* W2  = (const float*)d_in[4];
    const float* b2  = (const float*)d_in[5];
    const float* Wl1 = (const float*)d_in[6];
    const float* bl1 = (const float*)d_in[7];
    const float* Wl2 = (const float*)d_in[8];
    const float* bl2 = (const float*)d_in[9];
    float* out = (float*)d_out;

    const int N = in_sizes[0] / 128;
    const int E = in_sizes[1] / 2;
    const int* row = ei;
    const int* col = ei + E;
    const int nb = (N + 255) / 256;

    char* ws = (char*)d_ws;
    size_t off = 0;
    auto alloc = [&](size_t bytes) {
        void* p = ws + off;
        off += (bytes + 255) & ~(size_t)255;
        return p;
    };
    float* dinv = (float*)alloc((size_t)N * 4);
    int*   cnt  = (int*)alloc((size_t)N * 4);
    int*   offs = (int*)alloc((size_t)(N + 1) * 4);
    int*   cur  = (int*)alloc((size_t)N * 4);
    int*   bsum = (int*)alloc((size_t)nb * 4);
    int*   srow = (int*)alloc((size_t)E * 4);
    short* wb   = (short*)alloc((size_t)5 * 32768 * 2);
    float* bufA = (float*)alloc((size_t)N * 128 * 4);   // xws1 -> xws2
    float* bufB = (float*)alloc((size_t)N * 128 * 4);   // x1
    float* bufC = (float*)alloc((size_t)N * 128 * 4);   // x2

    const int B = 256;
    int gN = (N + B - 1) / B;
    int gE = (E + B - 1) / B;
    int gG = (N + 127) / 128;                           // MFMA gemm tiles
    int gA = (int)(((long long)N * 64 + B - 1) / B);    // wave per node
    int gP = (5 * 16384 + B - 1) / B;

    // ---- CSR build + weight prep ----
    hipMemsetAsync(cnt, 0, (size_t)N * 4, stream);
    hipMemsetAsync(cur, 0, (size_t)N * 4, stream);
    k_hist<<<gE, B, 0, stream>>>(col, cnt, E);
    k_dinv<<<gN, B, 0, stream>>>(cnt, dinv, N);
    k_scan1<<<nb, B, 0, stream>>>(cnt, offs, bsum, N);
    k_scan2<<<1, B, 0, stream>>>(bsum, nb);
    k_scan3<<<gN, B, 0, stream>>>(offs, bsum, N, E);
    k_fill<<<gE, B, 0, stream>>>(row, col, offs, cur, srow, E);
    k_prep_w<<<gP, B, 0, stream>>>(W1, W2, Wl1, wb);

    // ---- layer 1: xws1 = (x@W1)*dinv ; x1 = relu(dinv*(agg)+b1) ----
    k_gemm_mfma<<<gG, B, 0, stream>>>(x, nullptr, nullptr, wb,
                                      dinv, nullptr, nullptr, nullptr,
                                      bufA, N, 1, 0);
    k_aggregate<<<gA, B, 0, stream>>>(bufA, dinv, b1, offs, srow, bufB, N);

    // ---- layer 2 ----
    k_gemm_mfma<<<gG, B, 0, stream>>>(bufB, nullptr, nullptr, wb + 32768,
                                      dinv, nullptr, nullptr, nullptr,
                                      bufA, N, 1, 0);
    k_aggregate<<<gA, B, 0, stream>>>(bufA, dinv, b2, offs, srow, bufC, N);

    // ---- fused MLP head: out = sigmoid(relu([x,x1,x2]@Wl1+bl1)@Wl2+bl2) ----
    k_gemm_mfma<<<gG, B, 0, stream>>>(x, bufB, bufC, wb + 2 * 32768,
                                      nullptr, bl1, Wl2, bl2,
                                      out, N, 3, 1);
}